// Round 6
// baseline (187.641 us; speedup 1.0000x reference)
//
#include <hip/hip_runtime.h>

// CIF burst-mode neuron, closed form. Elementwise, memory-bound.
// All 12 streaming global_load_dwordx4 (+4 th loads) are issued, then an
// inline-asm memory-clobber fence (a legality barrier at IR AND machine
// level, unlike sched_barrier) prevents load sinking into the compute loop.

typedef float v4f __attribute__((ext_vector_type(4)));

constexpr int TPB = 256;
constexpr int UF  = 4;   // float4-chunks per thread

__device__ __forceinline__ float cif_one(float xv, float mv, float sv, float t) {
    float m = __fadd_rn(mv, xv);
    // k_pos = max(ceil((m - t)/t), 0)   -- exact RN divide (boundary-sensitive)
    float kpos = fmaxf(ceilf(__fdiv_rn(__fsub_rn(m, t), t)), 0.0f);
    float kpt = __fmul_rn(kpos, t);
    float m1  = __fsub_rn(m, kpt);
    // sc_units = round((sc + k_pos*t)/t): true quotient is a small integer;
    // v_rcp_f32 (1 ulp) error ~1e-5 << 0.5 so rintf unaffected.
    float rt = __builtin_amdgcn_rcpf(t);
    float sc_units = rintf(__fmul_rn(__fadd_rn(sv, kpt), rt));
    // j_mem = max(ceil((-m1 - t)/t), 0)  -- exact RN divide
    float jmem = fmaxf(ceilf(__fdiv_rn(__fsub_rn(-m1, t), t)), 0.0f);
    float kneg = fminf(jmem, fmaxf(sc_units, 0.0f));
    return __fmul_rn(__fsub_rn(kpos, kneg), t);
}

__device__ __forceinline__ v4f cif_vec(float4 xv, float4 mv, float4 sv, float4 tv) {
    v4f o;
    o.x = cif_one(xv.x, mv.x, sv.x, tv.x);
    o.y = cif_one(xv.y, mv.y, sv.y, tv.y);
    o.z = cif_one(xv.z, mv.z, sv.z, tv.z);
    o.w = cif_one(xv.w, mv.w, sv.w, tv.w);
    return o;
}

// Main kernel: no bounds checks; grid covers exactly blocks*TPB*UF chunks.
__global__ __launch_bounds__(TPB, 4) void CIFNeuron_36558761624015_main(
        const float4* __restrict__ x,
        const float4* __restrict__ mem,
        const float4* __restrict__ sc,
        const float*  __restrict__ th,
        float4* __restrict__ out,
        int hmask /* H-1 */) {
    const long long base = (long long)blockIdx.x * (TPB * UF) + threadIdx.x;

    float4 xv[UF], mv[UF], sv[UF], tv[UF];
    #pragma unroll
    for (int k = 0; k < UF; ++k) xv[k] = x[base + (long long)k * TPB];
    #pragma unroll
    for (int k = 0; k < UF; ++k) mv[k] = mem[base + (long long)k * TPB];
    #pragma unroll
    for (int k = 0; k < UF; ++k) sv[k] = sc[base + (long long)k * TPB];
    #pragma unroll
    for (int k = 0; k < UF; ++k) {
        int h = (int)(((base + (long long)k * TPB) * 4) & (long long)hmask);
        tv[k] = *reinterpret_cast<const float4*>(th + h);
    }

    // Legality fence: loads above cannot sink below (clobber may alias),
    // stores below cannot hoist above. Forces all 16 loads batch-issued.
    asm volatile("" ::: "memory");

    #pragma unroll
    for (int k = 0; k < UF; ++k) {
        v4f o = cif_vec(xv[k], mv[k], sv[k], tv[k]);
        __builtin_nontemporal_store(o, reinterpret_cast<v4f*>(out) + base + (long long)k * TPB);
    }
}

// Tail kernel: guarded, one chunk per thread.
__global__ __launch_bounds__(TPB) void CIFNeuron_36558761624015_tail(
        const float4* __restrict__ x,
        const float4* __restrict__ mem,
        const float4* __restrict__ sc,
        const float*  __restrict__ th,
        float4* __restrict__ out,
        long long start, long long n4, int hmask) {
    long long i = start + (long long)blockIdx.x * TPB + threadIdx.x;
    if (i < n4) {
        int h = (int)((i * 4) & (long long)hmask);
        float4 tv = *reinterpret_cast<const float4*>(th + h);
        v4f o = cif_vec(x[i], mem[i], sc[i], tv);
        __builtin_nontemporal_store(o, reinterpret_cast<v4f*>(out) + i);
    }
}

extern "C" void kernel_launch(void* const* d_in, const int* in_sizes, int n_in,
                              void* d_out, int out_size, void* d_ws, size_t ws_size,
                              hipStream_t stream) {
    const float* x   = (const float*)d_in[0];
    const float* mem = (const float*)d_in[1];
    const float* sc  = (const float*)d_in[2];
    const float* th  = (const float*)d_in[3];
    float* out = (float*)d_out;

    const int H = in_sizes[3];            // 4096
    long long n  = (long long)out_size;   // B*T*H, H%4==0
    long long n4 = n / 4;

    const long long per_block = (long long)TPB * UF;   // 1024 chunks
    long long full_blocks = n4 / per_block;
    long long rem_chunks  = n4 - full_blocks * per_block;

    if (full_blocks > 0) {
        CIFNeuron_36558761624015_main<<<(int)full_blocks, TPB, 0, stream>>>(
            (const float4*)x, (const float4*)mem, (const float4*)sc, th,
            (float4*)out, H - 1);
    }
    if (rem_chunks > 0) {
        int tail_blocks = (int)((rem_chunks + TPB - 1) / TPB);
        CIFNeuron_36558761624015_tail<<<tail_blocks, TPB, 0, stream>>>(
            (const float4*)x, (const float4*)mem, (const float4*)sc, th,
            (float4*)out, full_blocks * per_block, n4, H - 1);
    }
}

// Round 7
// 184.721 us; speedup vs baseline: 1.0158x; 1.0158x over previous
//
#include <hip/hip_runtime.h>

// CIF burst-mode neuron, closed form. Elementwise, memory-bound.
// The 12 streaming loads + 4 threshold loads are emitted as inline-asm
// global_load_dwordx4 (compiler cannot sink them or shrink live ranges),
// followed by one s_waitcnt vmcnt(0) that ties all results as "+v" operands
// so every consumer is data-dependent on the wait. This guarantees 16
// outstanding loads (~256B/lane) per wave — the conclusive MLP experiment.

typedef float v4f __attribute__((ext_vector_type(4)));

constexpr int TPB = 256;
constexpr int UF  = 4;   // float4-chunks per thread

__device__ __forceinline__ float cif_one(float xv, float mv, float sv, float t) {
    float m = __fadd_rn(mv, xv);
    // k_pos = max(ceil((m - t)/t), 0)   -- exact RN divide (boundary-sensitive)
    float kpos = fmaxf(ceilf(__fdiv_rn(__fsub_rn(m, t), t)), 0.0f);
    float kpt = __fmul_rn(kpos, t);
    float m1  = __fsub_rn(m, kpt);
    // sc_units = round((sc + k_pos*t)/t): true quotient is a small integer;
    // v_rcp_f32 (1 ulp) error ~1e-5 << 0.5 so rintf unaffected.
    float rt = __builtin_amdgcn_rcpf(t);
    float sc_units = rintf(__fmul_rn(__fadd_rn(sv, kpt), rt));
    // j_mem = max(ceil((-m1 - t)/t), 0)  -- exact RN divide
    float jmem = fmaxf(ceilf(__fdiv_rn(__fsub_rn(-m1, t), t)), 0.0f);
    float kneg = fminf(jmem, fmaxf(sc_units, 0.0f));
    return __fmul_rn(__fsub_rn(kpos, kneg), t);
}

__device__ __forceinline__ v4f cif_vec(v4f xv, v4f mv, v4f sv, v4f tv) {
    v4f o;
    o.x = cif_one(xv.x, mv.x, sv.x, tv.x);
    o.y = cif_one(xv.y, mv.y, sv.y, tv.y);
    o.z = cif_one(xv.z, mv.z, sv.z, tv.z);
    o.w = cif_one(xv.w, mv.w, sv.w, tv.w);
    return o;
}

#define GLOADX4(dst, p) \
    asm volatile("global_load_dwordx4 %0, %1, off" : "=v"(dst) : "v"(p))

// Main kernel: no bounds checks; grid covers exactly blocks*TPB*UF chunks.
__global__ __launch_bounds__(TPB, 4) void CIFNeuron_36558761624015_main(
        const float4* __restrict__ x,
        const float4* __restrict__ mem,
        const float4* __restrict__ sc,
        const float*  __restrict__ th,
        float4* __restrict__ out,
        int hmask /* H-1 */) {
    const long long base = (long long)blockIdx.x * (TPB * UF) + threadIdx.x;

    v4f xv[UF], mv[UF], sv[UF], tv[UF];

    // Batch-issue all 16 loads (asm volatile: ordered, un-sinkable).
    #pragma unroll
    for (int k = 0; k < UF; ++k) GLOADX4(xv[k], x   + base + (long long)k * TPB);
    #pragma unroll
    for (int k = 0; k < UF; ++k) GLOADX4(mv[k], mem + base + (long long)k * TPB);
    #pragma unroll
    for (int k = 0; k < UF; ++k) GLOADX4(sv[k], sc  + base + (long long)k * TPB);
    #pragma unroll
    for (int k = 0; k < UF; ++k) {
        int h = (int)(((base + (long long)k * TPB) * 4) & (long long)hmask);
        GLOADX4(tv[k], reinterpret_cast<const float4*>(th + h));
    }

    // Drain all loads; tying every result as "+v" makes all consumers
    // data-dependent on this wait (nothing can be scheduled before it).
    asm volatile("s_waitcnt vmcnt(0)"
                 : "+v"(xv[0]), "+v"(xv[1]), "+v"(xv[2]), "+v"(xv[3]),
                   "+v"(mv[0]), "+v"(mv[1]), "+v"(mv[2]), "+v"(mv[3]),
                   "+v"(sv[0]), "+v"(sv[1]), "+v"(sv[2]), "+v"(sv[3]),
                   "+v"(tv[0]), "+v"(tv[1]), "+v"(tv[2]), "+v"(tv[3]));

    #pragma unroll
    for (int k = 0; k < UF; ++k) {
        v4f o = cif_vec(xv[k], mv[k], sv[k], tv[k]);
        __builtin_nontemporal_store(o, reinterpret_cast<v4f*>(out) + base + (long long)k * TPB);
    }
}

// Tail kernel: guarded, one chunk per thread (plain C path).
__global__ __launch_bounds__(TPB) void CIFNeuron_36558761624015_tail(
        const float4* __restrict__ x,
        const float4* __restrict__ mem,
        const float4* __restrict__ sc,
        const float*  __restrict__ th,
        float4* __restrict__ out,
        long long start, long long n4, int hmask) {
    long long i = start + (long long)blockIdx.x * TPB + threadIdx.x;
    if (i < n4) {
        int h = (int)((i * 4) & (long long)hmask);
        const float4 t4 = *reinterpret_cast<const float4*>(th + h);
        float4 a = x[i], b = mem[i], c = sc[i];
        v4f xv = {a.x, a.y, a.z, a.w};
        v4f mv = {b.x, b.y, b.z, b.w};
        v4f svv = {c.x, c.y, c.z, c.w};
        v4f tv = {t4.x, t4.y, t4.z, t4.w};
        v4f o = cif_vec(xv, mv, svv, tv);
        __builtin_nontemporal_store(o, reinterpret_cast<v4f*>(out) + i);
    }
}

extern "C" void kernel_launch(void* const* d_in, const int* in_sizes, int n_in,
                              void* d_out, int out_size, void* d_ws, size_t ws_size,
                              hipStream_t stream) {
    const float* x   = (const float*)d_in[0];
    const float* mem = (const float*)d_in[1];
    const float* sc  = (const float*)d_in[2];
    const float* th  = (const float*)d_in[3];
    float* out = (float*)d_out;

    const int H = in_sizes[3];            // 4096
    long long n  = (long long)out_size;   // B*T*H, H%4==0
    long long n4 = n / 4;

    const long long per_block = (long long)TPB * UF;   // 1024 chunks
    long long full_blocks = n4 / per_block;
    long long rem_chunks  = n4 - full_blocks * per_block;

    if (full_blocks > 0) {
        CIFNeuron_36558761624015_main<<<(int)full_blocks, TPB, 0, stream>>>(
            (const float4*)x, (const float4*)mem, (const float4*)sc, th,
            (float4*)out, H - 1);
    }
    if (rem_chunks > 0) {
        int tail_blocks = (int)((rem_chunks + TPB - 1) / TPB);
        CIFNeuron_36558761624015_tail<<<tail_blocks, TPB, 0, stream>>>(
            (const float4*)x, (const float4*)mem, (const float4*)sc, th,
            (float4*)out, full_blocks * per_block, n4, H - 1);
    }
}